// Round 6
// baseline (432.647 us; speedup 1.0000x reference)
//
#include <hip/hip_runtime.h>

// pred_masks:   [B=8, NP=8, 512, 512] f32 logits
// target_masks: [B=8, NT=16, 512, 512] f32 in [0,1]
// out: scalar = 5 * mean_{b,i} min_j [ mean(softplus(p_i)) - <p_i,t_j>/HW ]
//      (all-zero targets j are skipped -> loss entry 0)
#define NB 8
#define NP 8
#define NT 16
#define HW (512 * 512)
#define HW4 (HW / 4)              // 65536 float4 per image
#define WIN 512                   // float4 window per image per block
#define CHUNKS (WIN / 64)         // 8 chunk-iters (64 lanes each)
#define BPB (HW4 / WIN)           // 128 blocks per batch
#define THREADS 1024              // 16 waves: wave j owns target j
#define NACC (NP + NP * NT + NT)  // 152

__device__ __forceinline__ void gload_lds16(const float* g, float* l) {
  // async global->LDS, 16B/lane; LDS dest = wave-uniform base (+lane*16 by HW)
  __builtin_amdgcn_global_load_lds(
      (const __attribute__((address_space(1))) void*)g,
      (__attribute__((address_space(3))) void*)l, 16, 0, 0);
}

__device__ __forceinline__ float softplus1(float x) {
  return fmaxf(x, 0.0f) + __logf(1.0f + __expf(-fabsf(x)));
}

__device__ __forceinline__ float wred(float v) {
#pragma unroll
  for (int off = 32; off > 0; off >>= 1) v += __shfl_down(v, off);
  return v;
}

// MLP-maximizing kernel. Block = (batch b, pixel window of 512 float4).
// Wave j (of 16) owns target j: issues all 8 of its 1KiB targ loads up-front
// (8 KiB in flight per wave ~ 256 KiB per CU) while pred window (8 x 8 KiB)
// is staged to LDS once via global_load_lds. One barrier per block. Waves
// 0..7 additionally fold softplus of pred image j from LDS.
__global__ __launch_bounds__(THREADS, 8) void sam_partial(
    const float* __restrict__ pred, const float* __restrict__ targ,
    float* __restrict__ ws) {
  const int tid  = threadIdx.x;
  const int lane = tid & 63;
  const int wv   = tid >> 6;             // wave id = target j (0..15)
  const int b    = blockIdx.x >> 7;      // blockIdx = b*BPB + w
  const int w    = blockIdx.x & (BPB - 1);
  const int wstart = w * WIN;            // float4 offset within image

  __shared__ float4 lds[NP * WIN];       // 64 KiB: [image i][512 float4]

  // ---- issue all 8 targ loads for this wave (independent VGPR targets) ----
  const float4* tj = reinterpret_cast<const float4*>(targ) +
                     ((size_t)(b * NT + wv)) * HW4 + wstart + lane;
  float4 t[CHUNKS];
#pragma unroll
  for (int k = 0; k < CHUNKS; ++k) t[k] = tj[(size_t)k * 64];

  // ---- stage pred window: wave wv stages 1KiB chunks {wv, wv+16, wv+32, wv+48} ----
#pragma unroll
  for (int r = 0; r < 4; ++r) {
    const int g = wv + (r << 4);         // 0..63
    const int i = g >> 3;                // pred image
    const int c = g & 7;                 // chunk within window
    const float* src = pred + ((size_t)(b * NP + i)) * HW +
                       (size_t)(wstart + c * 64) * 4 + lane * 4;
    gload_lds16(src, reinterpret_cast<float*>(&lds[(i * 8 + c) * 64]));
  }
  asm volatile("s_waitcnt vmcnt(0)" ::: "memory");
  __syncthreads();

  // ---- consume: dot[i] for target wv, ts, (waves<8) softplus ----
  float dot[NP];
#pragma unroll
  for (int i = 0; i < NP; ++i) dot[i] = 0.0f;
  float ts = 0.0f, sp = 0.0f;

#pragma unroll
  for (int k = 0; k < CHUNKS; ++k) {
    const float4 tv = t[k];
    ts += (tv.x + tv.y) + (tv.z + tv.w);
#pragma unroll
    for (int i = 0; i < NP; ++i) {
      const float4 p = lds[(i * 8 + k) * 64 + lane];
      dot[i] = fmaf(p.x, tv.x, fmaf(p.y, tv.y,
               fmaf(p.z, tv.z, fmaf(p.w, tv.w, dot[i]))));
    }
    if (wv < NP) {  // wave-uniform branch
      const float4 q = lds[(wv * 8 + k) * 64 + lane];
      sp += (softplus1(q.x) + softplus1(q.y)) +
            (softplus1(q.z) + softplus1(q.w));
    }
  }

  // ---- per-wave reduce + atomics ----
  float* wb = ws + (size_t)b * NACC;
#pragma unroll
  for (int i = 0; i < NP; ++i) {
    const float v = wred(dot[i]);
    if (lane == 0) atomicAdd(wb + NP + i * NT + wv, v);
  }
  {
    const float v = wred(ts);
    if (lane == 0) atomicAdd(wb + NP + NP * NT + wv, v);
  }
  if (wv < NP) {
    const float v = wred(sp);
    if (lane == 0) atomicAdd(wb + wv, v);
  }
}

// Stage 2: one wave; thread t owns (b = t>>3, i = t&7).
__global__ void sam_final(const float* __restrict__ ws,
                          float* __restrict__ out) {
  const int t = threadIdx.x;  // 64 threads
  const int b = t >> 3;
  const int i = t & 7;
  const float* w = ws + (size_t)b * NACC;
  const float spsum = w[i];
  float m = 3.4e38f;
#pragma unroll
  for (int j = 0; j < NT; ++j) {
    const float tsj = w[NP + NP * NT + j];
    const float v =
        (tsj == 0.0f) ? 0.0f : (spsum - w[NP + i * NT + j]) * (1.0f / HW);
    m = fminf(m, v);
  }
  float s = m;
#pragma unroll
  for (int off = 32; off > 0; off >>= 1) s += __shfl_down(s, off);
  if (t == 0) out[0] = 5.0f * s * (1.0f / 64.0f);
}

extern "C" void kernel_launch(void* const* d_in, const int* in_sizes, int n_in,
                              void* d_out, int out_size, void* d_ws,
                              size_t ws_size, hipStream_t stream) {
  const float* pred = (const float*)d_in[0];
  const float* targ = (const float*)d_in[1];
  float* out = (float*)d_out;
  float* ws = (float*)d_ws;

  hipMemsetAsync(ws, 0, (size_t)NB * NACC * sizeof(float), stream);
  sam_partial<<<dim3(NB * BPB), THREADS, 0, stream>>>(pred, targ, ws);
  sam_final<<<1, 64, 0, stream>>>(ws, out);
}

// Round 7
// 76.607 us; speedup vs baseline: 5.6476x; 5.6476x over previous
//
#include <hip/hip_runtime.h>

// pred_masks:   [B=8, NP=8, 512, 512] f32 logits
// target_masks: [B=8, NT=16, 512, 512] f32 in [0,1]
// out: scalar = 5 * mean_{b,i} min_j [ mean(softplus(p_i)) - <p_i,t_j>/HW ]
//      (all-zero targets j are skipped -> loss entry 0)
#define NB 8
#define NP 8
#define NT 16
#define HW (512 * 512)
#define HW4 (HW / 4)              // 65536 float4 per image
#define NACC (NP + NP * NT + NT)  // 152 accumulators per batch
#define BLOCKS_PER_B 64
#define THREADS 256
#define ITERS 4                   // 64 blk * 4 waves * 4 iters * 64 lanes = HW4

__device__ __forceinline__ float wred(float v) {
#pragma unroll
  for (int off = 32; off > 0; off >>= 1) v += __shfl_down(v, off);
  return v;
}

__device__ __forceinline__ float softplus1(float x) {
  // stable: max(x,0) + log(1 + exp(-|x|)); hw exp/log, err ~1e-6 rel.
  return fmaxf(x, 0.0f) + __logf(1.0f + __expf(-fabsf(x)));
}

__device__ __forceinline__ int bitrev6(int x) {
  x = ((x & 0x15) << 1) | ((x >> 1) & 0x15);          // swap within pairs
  x = ((x & 0x03) << 4) | (x & 0x0C) | ((x >> 4) & 3); // swap outer pairs of 2-bit groups
  return x & 63;
}

// R0 chassis (24 streams/thread, 152 accumulators, 8 waves/CU, no spills)
// with two address-schedule changes:
//  1. per-(wave,image) streams are CONTIGUOUS across iters (wave covers
//     wid*4KiB + it*1KiB) -> long sequential runs per stream head.
//  2. decorrelation: block->window map is bit-reversed and the chunk-visit
//     order is rotated per block, so concurrently-active blocks cover
//     well-spread address phases instead of advancing in lockstep.
__global__ __launch_bounds__(THREADS, 2) void sam_partial(
    const float* __restrict__ pred, const float* __restrict__ targ,
    float* __restrict__ ws) {
  const int b    = blockIdx.x / BLOCKS_PER_B;
  const int blk0 = blockIdx.x % BLOCKS_PER_B;
  const int blk  = bitrev6(blk0);          // decorrelate window starts
  const int tid  = threadIdx.x;
  const int lane = tid & 63;
  const int wid  = tid >> 6;

  float sp[NP];
  float ts[NT];
  float dot[NP][NT];
#pragma unroll
  for (int i = 0; i < NP; ++i) sp[i] = 0.0f;
#pragma unroll
  for (int j = 0; j < NT; ++j) ts[j] = 0.0f;
#pragma unroll
  for (int i = 0; i < NP; ++i)
#pragma unroll
    for (int j = 0; j < NT; ++j) dot[i][j] = 0.0f;

  const float4* __restrict__ pb =
      reinterpret_cast<const float4*>(pred) + (size_t)b * NP * HW4;
  const float4* __restrict__ tb =
      reinterpret_cast<const float4*>(targ) + (size_t)b * NT * HW4;

#pragma unroll 1
  for (int it = 0; it < ITERS; ++it) {
    const int it2 = (it + blk0) & (ITERS - 1);  // rotated chunk phase
    // wave-contiguous: wave wid owns [blk*16KiB + wid*4KiB, +4KiB)
    const int idx = blk * (THREADS * ITERS) + wid * (64 * ITERS) + it2 * 64 + lane;

    float4 p[NP];
#pragma unroll
    for (int i = 0; i < NP; ++i) p[i] = pb[(size_t)i * HW4 + idx];

#pragma unroll
    for (int j = 0; j < NT; ++j) {
      const float4 t = tb[(size_t)j * HW4 + idx];
      ts[j] += (t.x + t.y) + (t.z + t.w);
#pragma unroll
      for (int i = 0; i < NP; ++i) {
        dot[i][j] = fmaf(p[i].x, t.x,
                    fmaf(p[i].y, t.y,
                    fmaf(p[i].z, t.z,
                    fmaf(p[i].w, t.w, dot[i][j]))));
      }
    }
#pragma unroll
    for (int i = 0; i < NP; ++i) {
      sp[i] += (softplus1(p[i].x) + softplus1(p[i].y)) +
               (softplus1(p[i].z) + softplus1(p[i].w));
    }
  }

  // Block reduction: wave shuffle-reduce each accumulator, stash wave sums in
  // LDS, then threads 0..NACC-1 fold 4 waves and atomicAdd to global ws.
  __shared__ float red[4][NACC];

#pragma unroll
  for (int i = 0; i < NP; ++i) {
    float v = wred(sp[i]);
    if (lane == 0) red[wid][i] = v;
  }
#pragma unroll
  for (int i = 0; i < NP; ++i) {
#pragma unroll
    for (int j = 0; j < NT; ++j) {
      float v = wred(dot[i][j]);
      if (lane == 0) red[wid][NP + i * NT + j] = v;
    }
  }
#pragma unroll
  for (int j = 0; j < NT; ++j) {
    float v = wred(ts[j]);
    if (lane == 0) red[wid][NP + NP * NT + j] = v;
  }
  __syncthreads();
  if (tid < NACC) {
    float v = (red[0][tid] + red[1][tid]) + (red[2][tid] + red[3][tid]);
    atomicAdd(ws + (size_t)b * NACC + tid, v);
  }
}

// Stage 2: one wave; thread t owns (b = t>>3, i = t&7).
__global__ void sam_final(const float* __restrict__ ws,
                          float* __restrict__ out) {
  const int t = threadIdx.x;  // 64 threads
  const int b = t >> 3;
  const int i = t & 7;
  const float* w = ws + (size_t)b * NACC;
  const float spsum = w[i];
  float m = 3.4e38f;
#pragma unroll
  for (int j = 0; j < NT; ++j) {
    const float tsj = w[NP + NP * NT + j];
    const float v =
        (tsj == 0.0f) ? 0.0f : (spsum - w[NP + i * NT + j]) * (1.0f / HW);
    m = fminf(m, v);
  }
  float s = m;
#pragma unroll
  for (int off = 32; off > 0; off >>= 1) s += __shfl_down(s, off);
  if (t == 0) out[0] = 5.0f * s * (1.0f / 64.0f);
}

extern "C" void kernel_launch(void* const* d_in, const int* in_sizes, int n_in,
                              void* d_out, int out_size, void* d_ws,
                              size_t ws_size, hipStream_t stream) {
  const float* pred = (const float*)d_in[0];
  const float* targ = (const float*)d_in[1];
  float* out = (float*)d_out;
  float* ws = (float*)d_ws;

  hipMemsetAsync(ws, 0, (size_t)NB * NACC * sizeof(float), stream);
  sam_partial<<<dim3(NB * BLOCKS_PER_B), THREADS, 0, stream>>>(pred, targ, ws);
  sam_final<<<1, 64, 0, stream>>>(ws, out);
}

// Round 8
// 75.651 us; speedup vs baseline: 5.7190x; 1.0126x over previous
//
#include <hip/hip_runtime.h>

// pred_masks:   [B=8, NP=8, 512, 512] f32 logits
// target_masks: [B=8, NT=16, 512, 512] f32 in [0,1]
// out: scalar = 5 * mean_{b,i} min_j [ mean(softplus(p_i)) - <p_i,t_j>/HW ]
//      (all-zero targets j are skipped -> loss entry 0)
#define NB 8
#define NP 8
#define NT 16
#define NIMG (NP + NT)           // 24 images per batch
#define HW (512 * 512)           // floats per image
#define CHF 256                  // floats per image-chunk (1 KiB)
#define CH4 (CHF / 4)            // 64 float4 per image-chunk
#define NCH (HW / CHF)           // 1024 chunks per image
#define CPB 16                   // chunks per block
#define BPB (NCH / CPB)          // 64 blocks per batch
#define THREADS 512              // 8 waves
#define NACC (NP + NP * NT + NT) // 152

__device__ __forceinline__ void gload_lds16(const float* g, float* l) {
  // async global->LDS, 16B/lane; LDS dest = wave-uniform base (+lane*16 by HW)
  __builtin_amdgcn_global_load_lds(
      (const __attribute__((address_space(1))) void*)g,
      (__attribute__((address_space(3))) void*)l, 16, 0, 0);
}

__device__ __forceinline__ float softplus1(float x) {
  return fmaxf(x, 0.0f) + __logf(1.0f + __expf(-fabsf(x)));
}

__device__ __forceinline__ float wred(float v) {
#pragma unroll
  for (int off = 32; off > 0; off >>= 1) v += __shfl_down(v, off);
  return v;
}

// Double-buffered staging kernel. Per chunk-iter: issue async stage of chunk
// k+1 (24 x 1KiB via global_load_lds, 3 per wave), then consume chunk k from
// LDS: wave w owns targets {2w, 2w+1} (16 dots + 2 target sums) + softplus of
// pred image w. One __syncthreads per chunk; its vmcnt drain lands AFTER the
// compute phase, so staging latency hides under consumption. 19 accumulators
// per thread -> no register famine, no WAR-serialized loads.
__global__ __launch_bounds__(THREADS, 4) void sam_partial(
    const float* __restrict__ pred, const float* __restrict__ targ,
    float* __restrict__ ws) {
  const int tid  = threadIdx.x;
  const int lane = tid & 63;
  const int wid  = tid >> 6;            // wave id 0..7
  const int b    = blockIdx.x / BPB;
  const int c0   = (blockIdx.x % BPB) * CPB;

  __shared__ float lds[2][NIMG * CHF];  // 2 x 24 KiB

  float dot0[NP], dot1[NP];
#pragma unroll
  for (int i = 0; i < NP; ++i) { dot0[i] = 0.0f; dot1[i] = 0.0f; }
  float ts0 = 0.0f, ts1 = 0.0f, sp = 0.0f;

#define STAGE(c, s)                                                        \
  {                                                                        \
    _Pragma("unroll")                                                      \
    for (int r = 0; r < 3; ++r) {                                          \
      const int m = r * 8 + wid; /* image 0..23 */                         \
      const float* src =                                                   \
          (m < NP) ? pred + ((size_t)b * NP + m) * HW + (size_t)(c)*CHF +  \
                         lane * 4                                          \
                   : targ + ((size_t)b * NT + (m - NP)) * HW +             \
                         (size_t)(c)*CHF + lane * 4;                       \
      gload_lds16(src, &lds[(s)][m * CHF]);                                \
    }                                                                      \
  }

  STAGE(c0, 0);
  __syncthreads();  // drains vmcnt + joins waves: buffer 0 ready

#pragma unroll 1
  for (int k = 0; k < CPB; ++k) {
    const int s = k & 1;
    if (k + 1 < CPB) STAGE(c0 + k + 1, s ^ 1);  // async prefetch next chunk

    const float4* l4 = reinterpret_cast<const float4*>(lds[s]);
    float4 p[NP];
#pragma unroll
    for (int i = 0; i < NP; ++i) p[i] = l4[i * CH4 + lane];
    const float4 t0 = l4[(NP + 2 * wid) * CH4 + lane];
    const float4 t1 = l4[(NP + 2 * wid + 1) * CH4 + lane];
    const float4 q  = l4[wid * CH4 + lane];  // own pred via LDS (dynamic ok)

    ts0 += (t0.x + t0.y) + (t0.z + t0.w);
    ts1 += (t1.x + t1.y) + (t1.z + t1.w);
#pragma unroll
    for (int i = 0; i < NP; ++i) {
      dot0[i] = fmaf(p[i].x, t0.x, fmaf(p[i].y, t0.y,
                fmaf(p[i].z, t0.z, fmaf(p[i].w, t0.w, dot0[i]))));
      dot1[i] = fmaf(p[i].x, t1.x, fmaf(p[i].y, t1.y,
                fmaf(p[i].z, t1.z, fmaf(p[i].w, t1.w, dot1[i]))));
    }
    sp += (softplus1(q.x) + softplus1(q.y)) +
          (softplus1(q.z) + softplus1(q.w));

    __syncthreads();  // next buffer staged + this buffer free for reuse
  }
#undef STAGE

  // ---- per-wave reduce + atomics ----
  float* wb = ws + (size_t)b * NACC;
#pragma unroll
  for (int i = 0; i < NP; ++i) {
    const float v = wred(dot0[i]);
    if (lane == 0) atomicAdd(wb + NP + i * NT + 2 * wid, v);
  }
#pragma unroll
  for (int i = 0; i < NP; ++i) {
    const float v = wred(dot1[i]);
    if (lane == 0) atomicAdd(wb + NP + i * NT + 2 * wid + 1, v);
  }
  {
    const float v = wred(ts0);
    if (lane == 0) atomicAdd(wb + NP + NP * NT + 2 * wid, v);
  }
  {
    const float v = wred(ts1);
    if (lane == 0) atomicAdd(wb + NP + NP * NT + 2 * wid + 1, v);
  }
  {
    const float v = wred(sp);
    if (lane == 0) atomicAdd(wb + wid, v);
  }
}

// Stage 2: one wave; thread t owns (b = t>>3, i = t&7).
__global__ void sam_final(const float* __restrict__ ws,
                          float* __restrict__ out) {
  const int t = threadIdx.x;  // 64 threads
  const int b = t >> 3;
  const int i = t & 7;
  const float* w = ws + (size_t)b * NACC;
  const float spsum = w[i];
  float m = 3.4e38f;
#pragma unroll
  for (int j = 0; j < NT; ++j) {
    const float tsj = w[NP + NP * NT + j];
    const float v =
        (tsj == 0.0f) ? 0.0f : (spsum - w[NP + i * NT + j]) * (1.0f / HW);
    m = fminf(m, v);
  }
  float s = m;
#pragma unroll
  for (int off = 32; off > 0; off >>= 1) s += __shfl_down(s, off);
  if (t == 0) out[0] = 5.0f * s * (1.0f / 64.0f);
}

extern "C" void kernel_launch(void* const* d_in, const int* in_sizes, int n_in,
                              void* d_out, int out_size, void* d_ws,
                              size_t ws_size, hipStream_t stream) {
  const float* pred = (const float*)d_in[0];
  const float* targ = (const float*)d_in[1];
  float* out = (float*)d_out;
  float* ws = (float*)d_ws;

  hipMemsetAsync(ws, 0, (size_t)NB * NACC * sizeof(float), stream);
  sam_partial<<<dim3(NB * BPB), THREADS, 0, stream>>>(pred, targ, ws);
  sam_final<<<1, 64, 0, stream>>>(ws, out);
}

// Round 9
// 73.748 us; speedup vs baseline: 5.8666x; 1.0258x over previous
//
#include <hip/hip_runtime.h>

// pred_masks:   [B=8, NP=8, 512, 512] f32 logits
// target_masks: [B=8, NT=16, 512, 512] f32 in [0,1]
// out: scalar = 5 * mean_{b,i} min_j [ mean(softplus(p_i)) - <p_i,t_j>/HW ]
//      (all-zero targets j are skipped -> loss entry 0)
//
// R8 = R0 chassis (best so far, 73 us) + XCD-affinity block remap:
// blockIdx.x = window*8 + batch, so all 64 blocks of batch b dispatch to
// XCD b (round-robin block->XCD). Tests the L3-partition-thrash hypothesis:
// each 4-XCD group's L3 partition then only sees its own 4 batches (96 MiB).
#define NB 8
#define NP 8
#define NT 16
#define HW (512 * 512)
#define HW4 (HW / 4)              // 65536 float4 per image
#define NACC (NP + NP * NT + NT)  // 152 accumulators per batch
#define BLOCKS_PER_B 64
#define THREADS 256
#define ITERS 4                   // 64 blocks * 256 thr * 4 iters = 65536 = HW4

__device__ __forceinline__ float wred(float v) {
#pragma unroll
  for (int off = 32; off > 0; off >>= 1) v += __shfl_down(v, off);
  return v;
}

__device__ __forceinline__ float softplus1(float x) {
  // stable: max(x,0) + log(1 + exp(-|x|)); hw exp/log, err ~1e-6 rel.
  return fmaxf(x, 0.0f) + __logf(1.0f + __expf(-fabsf(x)));
}

__global__ __launch_bounds__(THREADS, 2) void sam_partial(
    const float* __restrict__ pred, const float* __restrict__ targ,
    float* __restrict__ ws) {
  // XCD-affinity mapping: batch = low 3 bits -> block lands on XCD = b.
  const int b   = blockIdx.x & 7;
  const int blk = blockIdx.x >> 3;
  const int tid = threadIdx.x;

  float sp[NP];
  float ts[NT];
  float dot[NP][NT];
#pragma unroll
  for (int i = 0; i < NP; ++i) sp[i] = 0.0f;
#pragma unroll
  for (int j = 0; j < NT; ++j) ts[j] = 0.0f;
#pragma unroll
  for (int i = 0; i < NP; ++i)
#pragma unroll
    for (int j = 0; j < NT; ++j) dot[i][j] = 0.0f;

  const float4* __restrict__ pb =
      reinterpret_cast<const float4*>(pred) + (size_t)b * NP * HW4;
  const float4* __restrict__ tb =
      reinterpret_cast<const float4*>(targ) + (size_t)b * NT * HW4;

#pragma unroll 1
  for (int it = 0; it < ITERS; ++it) {
    const int idx = blk * (THREADS * ITERS) + it * THREADS + tid;
    float4 p[NP];
#pragma unroll
    for (int i = 0; i < NP; ++i) p[i] = pb[(size_t)i * HW4 + idx];
#pragma unroll
    for (int i = 0; i < NP; ++i) {
      sp[i] += (softplus1(p[i].x) + softplus1(p[i].y)) +
               (softplus1(p[i].z) + softplus1(p[i].w));
    }
#pragma unroll
    for (int j = 0; j < NT; ++j) {
      const float4 t = tb[(size_t)j * HW4 + idx];
      ts[j] += (t.x + t.y) + (t.z + t.w);
#pragma unroll
      for (int i = 0; i < NP; ++i) {
        dot[i][j] = fmaf(p[i].x, t.x,
                    fmaf(p[i].y, t.y,
                    fmaf(p[i].z, t.z,
                    fmaf(p[i].w, t.w, dot[i][j]))));
      }
    }
  }

  // Block reduction: wave shuffle-reduce each accumulator, stash wave sums in
  // LDS, then threads 0..NACC-1 fold 4 waves and atomicAdd to global ws.
  __shared__ float red[4][NACC];
  const int lane = tid & 63;
  const int wid  = tid >> 6;

#pragma unroll
  for (int i = 0; i < NP; ++i) {
    float v = wred(sp[i]);
    if (lane == 0) red[wid][i] = v;
  }
#pragma unroll
  for (int i = 0; i < NP; ++i) {
#pragma unroll
    for (int j = 0; j < NT; ++j) {
      float v = wred(dot[i][j]);
      if (lane == 0) red[wid][NP + i * NT + j] = v;
    }
  }
#pragma unroll
  for (int j = 0; j < NT; ++j) {
    float v = wred(ts[j]);
    if (lane == 0) red[wid][NP + NP * NT + j] = v;
  }
  __syncthreads();
  if (tid < NACC) {
    float v = (red[0][tid] + red[1][tid]) + (red[2][tid] + red[3][tid]);
    atomicAdd(ws + (size_t)b * NACC + tid, v);
  }
}

// Stage 2: one wave; thread t owns (b = t>>3, i = t&7).
__global__ void sam_final(const float* __restrict__ ws,
                          float* __restrict__ out) {
  const int t = threadIdx.x;  // 64 threads
  const int b = t >> 3;
  const int i = t & 7;
  const float* w = ws + (size_t)b * NACC;
  const float spsum = w[i];
  float m = 3.4e38f;
#pragma unroll
  for (int j = 0; j < NT; ++j) {
    const float tsj = w[NP + NP * NT + j];
    const float v =
        (tsj == 0.0f) ? 0.0f : (spsum - w[NP + i * NT + j]) * (1.0f / HW);
    m = fminf(m, v);
  }
  float s = m;
#pragma unroll
  for (int off = 32; off > 0; off >>= 1) s += __shfl_down(s, off);
  if (t == 0) out[0] = 5.0f * s * (1.0f / 64.0f);
}

extern "C" void kernel_launch(void* const* d_in, const int* in_sizes, int n_in,
                              void* d_out, int out_size, void* d_ws,
                              size_t ws_size, hipStream_t stream) {
  const float* pred = (const float*)d_in[0];
  const float* targ = (const float*)d_in[1];
  float* out = (float*)d_out;
  float* ws = (float*)d_ws;

  hipMemsetAsync(ws, 0, (size_t)NB * NACC * sizeof(float), stream);
  sam_partial<<<dim3(NB * BLOCKS_PER_B), THREADS, 0, stream>>>(pred, targ, ws);
  sam_final<<<1, 64, 0, stream>>>(ws, out);
}